// Round 3
// baseline (453.448 us; speedup 1.0000x reference)
//
#include <hip/hip_runtime.h>
#include <math.h>

#define H 4096
#define E 64
#define BMROWS 16      // rows per block (1 mfma m-tile)
#define NT 256         // 4 waves; each wave owns a k-quarter
#define KQ 1024        // k per wave
#define BK 32          // k per window (one mfma k-step)
#define NWIN (KQ / BK) // 32 windows

typedef short bf16x8 __attribute__((ext_vector_type(8)));
typedef float f32x4  __attribute__((ext_vector_type(4)));

__device__ __forceinline__ unsigned f2bf_rne_u(float f) {
    unsigned u = __float_as_uint(f);
    return (u + 0x7fffu + ((u >> 16) & 1u)) >> 16;
}

// ---- kernel 1: w fp32 [64][4096] -> w_hi, w_lo bf16 (bits in ushort) ----
__global__ __launch_bounds__(256) void convert_w(const float* __restrict__ w,
                                                 unsigned short* __restrict__ wh,
                                                 unsigned short* __restrict__ wl) {
    const int i = (blockIdx.x * 256 + threadIdx.x) * 4;
    float4 v = *(const float4*)(w + i);
    float vv[4] = {v.x, v.y, v.z, v.w};
    unsigned hh[4], ll[4];
#pragma unroll
    for (int j = 0; j < 4; ++j) {
        hh[j] = f2bf_rne_u(vv[j]);
        float r = vv[j] - __uint_as_float(hh[j] << 16);
        ll[j] = __float_as_uint(r) >> 16;   // truncation: fine for residual
    }
    ushort4 h, l;
    h.x = (unsigned short)hh[0]; h.y = (unsigned short)hh[1];
    h.z = (unsigned short)hh[2]; h.w = (unsigned short)hh[3];
    l.x = (unsigned short)ll[0]; l.y = (unsigned short)ll[1];
    l.z = (unsigned short)ll[2]; l.w = (unsigned short)ll[3];
    *(ushort4*)(wh + i) = h;
    *(ushort4*)(wl + i) = l;
}

// 5-op/elem hi/lo split (numerically identical to prior rounds):
// hi = RNE-bf16(v), hi-as-float = t & 0xffff0000, lo = trunc-bf16(v - hi).
__device__ __forceinline__ void cvt8(const float4 a, const float4 b,
                                     bf16x8& hi, bf16x8& lo) {
    float v[8] = {a.x, a.y, a.z, a.w, b.x, b.y, b.z, b.w};
#pragma unroll
    for (int i = 0; i < 8; ++i) {
        const unsigned u = __float_as_uint(v[i]);
        const unsigned t = u + 0x7fffu + ((u >> 16) & 1u); // rounded bf16 in t[31:16]
        const float    r = v[i] - __uint_as_float(t & 0xffff0000u);
        hi[i] = (short)(t >> 16);
        lo[i] = (short)(__float_as_uint(r) >> 16);
    }
}

// ---- kernel 2: fused hi/lo bf16 MFMA GEMM + top-2 + softmax ----
// Occupancy-first restructure: 16 rows x 64 experts per block, 4 waves split
// K. Grid = 1024 blocks = 4 blocks/CU at <=128 VGPR -> 16 waves/CU (2x the
// previous version). Per-wave ILP is shallower (w single-buffered); residual
// latency is hidden by TLP. x: 4-buffer ring, prefetch distance 3.
__global__ __launch_bounds__(NT, 4) void router_kernel(
    const float* __restrict__ x,
    const unsigned short* __restrict__ wh,
    const unsigned short* __restrict__ wl,
    float* __restrict__ out, int M)
{
    __shared__ __align__(16) f32x4 merge[4][4][64];   // [nt][wave][lane]

    const int t    = threadIdx.x;
    const int lane = t & 63;
    const int wk   = t >> 6;        // k-quarter 0..3
    const int m0   = blockIdx.x * BMROWS;
    const int col  = lane & 15;
    const int quad = lane >> 4;     // 0..3

    const int kbase = wk * KQ + quad * 8;

    const float* xp = x + (size_t)(m0 + col) * H + kbase;
    const unsigned short* whp = wh + (size_t)col * H + kbase;
    const unsigned short* wlp = wl + (size_t)col * H + kbase;

    f32x4 acc[4];
#pragma unroll
    for (int nt = 0; nt < 4; ++nt)
        acc[nt] = (f32x4){0.0f, 0.0f, 0.0f, 0.0f};

    // x prefetch ring (distance 3); w single-buffered. All names are
    // compile-time so everything stays in VGPRs (no scratch).
    float4 x0[2], x1[2], x2[2], x3[2];
    uint4  wr[8];   // [0..3] = hi n-tiles, [4..7] = lo n-tiles

    auto loadx_into = [&](int win, float4 (&xb)[2]) {
        const int k = win * BK;
        xb[0] = *(const float4*)(xp + k);
        xb[1] = *(const float4*)(xp + k + 4);
    };
    auto loadw = [&](int win) {
        const int k = win * BK;
#pragma unroll
        for (int nt = 0; nt < 4; ++nt) {
            wr[nt]     = *(const uint4*)(whp + (size_t)(nt * 16) * H + k);
            wr[nt + 4] = *(const uint4*)(wlp + (size_t)(nt * 16) * H + k);
        }
    };

    // One window: w loads issue FIRST (so the MFMA's vmcnt wait keeps the x
    // prefetches in flight), then the x prefetch at distance 3, then cvt of
    // the current x (~180 cyc, covers most of the w L2 latency), then MFMA.
    auto step = [&](int win, float4 (&xc)[2], float4 (&xpref)[2]) {
        loadw(win);
        if (win + 3 < NWIN) loadx_into(win + 3, xpref);
        bf16x8 ah, al;
        cvt8(xc[0], xc[1], ah, al);
#pragma unroll
        for (int nt = 0; nt < 4; ++nt) {
            const bf16x8 bh = __builtin_bit_cast(bf16x8, wr[nt]);
            const bf16x8 bl = __builtin_bit_cast(bf16x8, wr[nt + 4]);
            acc[nt] = __builtin_amdgcn_mfma_f32_16x16x32_bf16(ah, bh, acc[nt], 0, 0, 0);
            acc[nt] = __builtin_amdgcn_mfma_f32_16x16x32_bf16(ah, bl, acc[nt], 0, 0, 0);
            acc[nt] = __builtin_amdgcn_mfma_f32_16x16x32_bf16(al, bh, acc[nt], 0, 0, 0);
        }
    };

    loadx_into(0, x0);
    loadx_into(1, x1);
    loadx_into(2, x2);

#pragma unroll 1
    for (int win = 0; win < NWIN; win += 4) {
        step(win,     x0, x3);
        step(win + 1, x1, x0);
        step(win + 2, x2, x1);
        step(win + 3, x3, x2);
    }

    // ---- cross-wave k-merge via LDS (conflict-free layout) ----
#pragma unroll
    for (int nt = 0; nt < 4; ++nt)
        merge[nt][wk][lane] = acc[nt];
    __syncthreads();

    if (wk != 0) return;

    f32x4 a2[4];
#pragma unroll
    for (int nt = 0; nt < 4; ++nt) {
        f32x4 s = acc[nt];                      // own quarter (== merge[nt][0])
#pragma unroll
        for (int w = 1; w < 4; ++w)
            s += merge[nt][w][lane];
        a2[nt] = s;
    }

    float* logits   = out;
    float* idx_out  = out + (size_t)M * E;
    float* prob_out = idx_out + (size_t)M * 2;

    const int mrow = m0 + quad * 4;
#pragma unroll
    for (int r = 0; r < 4; ++r) {
#pragma unroll
        for (int nt = 0; nt < 4; ++nt)
            logits[(size_t)(mrow + r) * E + nt * 16 + col] = a2[nt][r];

        // per-lane top-2 over its 4 experts (ascending index)
        float v1 = a2[0][r], v2 = -INFINITY;
        int   i1 = col,      i2 = 0x7fffffff;
#pragma unroll
        for (int nt = 1; nt < 4; ++nt) {
            const float v = a2[nt][r];
            const int   e = nt * 16 + col;
            if (v > v1)      { v2 = v1; i2 = i1; v1 = v; i1 = e; }
            else if (v > v2) { v2 = v;  i2 = e; }
        }
        // butterfly merge across the 16-lane row group
#pragma unroll
        for (int mask = 1; mask < 16; mask <<= 1) {
            const float ov1 = __shfl_xor(v1, mask);
            const float ov2 = __shfl_xor(v2, mask);
            const int   oi1 = __shfl_xor(i1, mask);
            const int   oi2 = __shfl_xor(i2, mask);
            const bool afirst = (v1 > ov1) || (v1 == ov1 && i1 < oi1);
            float nv1, nv2; int ni1, ni2;
            if (afirst) {
                nv1 = v1; ni1 = i1;
                const bool s = (v2 > ov1) || (v2 == ov1 && i2 < oi1);
                nv2 = s ? v2 : ov1; ni2 = s ? i2 : oi1;
            } else {
                nv1 = ov1; ni1 = oi1;
                const bool s = (ov2 > v1) || (ov2 == v1 && oi2 < i1);
                nv2 = s ? ov2 : v1; ni2 = s ? oi2 : i1;
            }
            v1 = nv1; v2 = nv2; i1 = ni1; i2 = ni2;
        }
        if (col == 0) {
            const int m = mrow + r;
            const float e2 = __expf(v2 - v1);   // <= 1
            const float d  = 1.0f + e2;
            *(float2*)(idx_out  + (size_t)m * 2) = make_float2((float)i1, (float)i2);
            *(float2*)(prob_out + (size_t)m * 2) = make_float2(1.0f / d, e2 / d);
        }
    }
}

extern "C" void kernel_launch(void* const* d_in, const int* in_sizes, int n_in,
                              void* d_out, int out_size, void* d_ws, size_t ws_size,
                              hipStream_t stream) {
    const float* x = (const float*)d_in[0];
    const float* w = (const float*)d_in[1];
    unsigned short* wh = (unsigned short*)d_ws;           // 512 KB
    unsigned short* wl = wh + (size_t)E * H;              // 512 KB
    const int M = in_sizes[0] / H;                        // 16384 rows

    hipLaunchKernelGGL(convert_w, dim3((E * H) / 1024), dim3(256), 0, stream,
                       w, wh, wl);
    hipLaunchKernelGGL(router_kernel, dim3(M / BMROWS), dim3(NT), 0, stream,
                       x, wh, wl, (float*)d_out, M);
}

// Round 5
// 402.023 us; speedup vs baseline: 1.1279x; 1.1279x over previous
//
#include <hip/hip_runtime.h>
#include <math.h>

#define H 4096
#define E 64
#define BMROWS 32      // rows per block (2 mfma m-tiles)
#define NT 256         // 4 waves; each wave owns a k-quarter
#define KQ 1024        // k per wave
#define BK 32          // floats per window (one mfma k-step after cvt)
#define NWIN (KQ / BK) // 32 windows

typedef short bf16x8 __attribute__((ext_vector_type(8)));
typedef float f32x4  __attribute__((ext_vector_type(4)));

#define GLBP(p) ((const __attribute__((address_space(1))) void*)(p))
#define LDSP(p) ((__attribute__((address_space(3))) void*)(p))

__device__ __forceinline__ unsigned f2bf_rne_u(float f) {
    unsigned u = __float_as_uint(f);
    return (u + 0x7fffu + ((u >> 16) & 1u)) >> 16;
}

// ---- kernel 1: w fp32 [64][4096] -> w_hi, w_lo bf16 (bits in ushort) ----
__global__ __launch_bounds__(256) void convert_w(const float* __restrict__ w,
                                                 unsigned short* __restrict__ wh,
                                                 unsigned short* __restrict__ wl) {
    const int i = (blockIdx.x * 256 + threadIdx.x) * 4;
    float4 v = *(const float4*)(w + i);
    float vv[4] = {v.x, v.y, v.z, v.w};
    unsigned hh[4], ll[4];
#pragma unroll
    for (int j = 0; j < 4; ++j) {
        hh[j] = f2bf_rne_u(vv[j]);
        float r = vv[j] - __uint_as_float(hh[j] << 16);
        ll[j] = __float_as_uint(r) >> 16;   // truncation: fine for residual
    }
    ushort4 h, l;
    h.x = (unsigned short)hh[0]; h.y = (unsigned short)hh[1];
    h.z = (unsigned short)hh[2]; h.w = (unsigned short)hh[3];
    l.x = (unsigned short)ll[0]; l.y = (unsigned short)ll[1];
    l.z = (unsigned short)ll[2]; l.w = (unsigned short)ll[3];
    *(ushort4*)(wh + i) = h;
    *(ushort4*)(wl + i) = l;
}

// 5-op/elem hi/lo split (numerically identical to prior rounds):
// hi = RNE-bf16(v), hi-as-float = t & 0xffff0000, lo = trunc-bf16(v - hi).
__device__ __forceinline__ void cvt8(const f32x4 a, const f32x4 b,
                                     bf16x8& hi, bf16x8& lo) {
    float v[8] = {a[0], a[1], a[2], a[3], b[0], b[1], b[2], b[3]};
#pragma unroll
    for (int i = 0; i < 8; ++i) {
        const unsigned u = __float_as_uint(v[i]);
        const unsigned t = u + 0x7fffu + ((u >> 16) & 1u); // rounded bf16 in t[31:16]
        const float    r = v[i] - __uint_as_float(t & 0xffff0000u);
        hi[i] = (short)(t >> 16);
        lo[i] = (short)(__float_as_uint(r) >> 16);
    }
}

// ---- kernel 2: fused hi/lo bf16 MFMA GEMM + top-2 + softmax ----
// x is staged global->LDS with __builtin_amdgcn_global_load_lds (the compiler
// cannot delete/sink this, unlike the register prefetch ring it deleted in
// rounds 0-2 — VGPR_Count=60 proved the ring was gone). Triple-buffered,
// prefetch distance 2, wave-private regions (no barriers in the main loop).
// LDS reads are swizzled (chunk ^ row&7) via pre-swizzled global source +
// linear LDS dest, so the ds_read_b128 fragment reads are conflict-free.
__global__ __launch_bounds__(NT, 2) void router_kernel(
    const float* __restrict__ x,
    const unsigned short* __restrict__ wh,
    const unsigned short* __restrict__ wl,
    float* __restrict__ out, int M)
{
    // 3 bufs x 4 waves x 1024 floats (4 KB) = 48 KB; reused for the k-merge.
    __shared__ __align__(16) float smem[3 * 4 * 1024];

    const int t    = threadIdx.x;
    const int lane = t & 63;
    const int wk   = t >> 6;        // k-quarter 0..3
    const int m0   = blockIdx.x * BMROWS;
    const int col  = lane & 15;
    const int quad = lane >> 4;     // 0..3

    // ---- staging source (pre-swizzled per-lane global addr; LDS linear) ----
    // stage call j fills rows j*8..j*8+7 of the 32x32f window; lane ->
    // (row = j*8 + lane>>3, slot-chunk = lane&7) holds global chunk
    // cg = (lane&7) ^ (row&7). 16B per lane per call.
    const int srow = lane >> 3;
    const int scg  = (lane & 7) ^ srow;
    const float* gx = x + (size_t)(m0 + srow) * H + wk * KQ + scg * 4;

    // ---- read-side swizzled slot indices (f32x4 units, lane-constant) ----
    const int r7 = col & 7;
    const int sl00 = (col     ) * 8 + ((2 * quad    ) ^ r7);
    const int sl01 = (col     ) * 8 + ((2 * quad + 1) ^ r7);
    const int sl10 = (col + 16) * 8 + ((2 * quad    ) ^ r7);
    const int sl11 = (col + 16) * 8 + ((2 * quad + 1) ^ r7);

    const unsigned short* whp = wh + (size_t)col * H + wk * KQ + quad * 8;
    const unsigned short* wlp = wl + (size_t)col * H + wk * KQ + quad * 8;

    f32x4 acc[2][4];
#pragma unroll
    for (int mt = 0; mt < 2; ++mt)
#pragma unroll
        for (int nt = 0; nt < 4; ++nt)
            acc[mt][nt] = (f32x4){0.0f, 0.0f, 0.0f, 0.0f};

    uint4 wrA[8], wrB[8];   // w hi/lo ping-pong (distance 1, L2-resident)

    auto stage = [&](int win, int b) {
        float* l = smem + (b * 4 + wk) * 1024;
        const float* g = gx + (size_t)win * BK;
#pragma unroll
        for (int j = 0; j < 4; ++j)
            __builtin_amdgcn_global_load_lds(GLBP(g + (size_t)j * 8 * H),
                                             LDSP(l + j * 256), 16, 0, 0);
    };
    auto loadw = [&](int win, uint4 (&wr)[8]) {
        const size_t k = (size_t)win * BK;
#pragma unroll
        for (int nt = 0; nt < 4; ++nt) {
            wr[nt]     = *(const uint4*)(whp + (size_t)nt * 16 * H + k);
            wr[nt + 4] = *(const uint4*)(wlp + (size_t)nt * 16 * H + k);
        }
    };
    auto compute = [&](int b, const uint4 (&wr)[8]) {
        const f32x4* sv = (const f32x4*)smem + (size_t)(b * 4 + wk) * 256;
        const f32x4 c00 = sv[sl00], c01 = sv[sl01];
        const f32x4 c10 = sv[sl10], c11 = sv[sl11];
        bf16x8 ah[2], al[2];
        cvt8(c00, c01, ah[0], al[0]);
        cvt8(c10, c11, ah[1], al[1]);
#pragma unroll
        for (int nt = 0; nt < 4; ++nt) {
            const bf16x8 bh = __builtin_bit_cast(bf16x8, wr[nt]);
            const bf16x8 bl = __builtin_bit_cast(bf16x8, wr[nt + 4]);
#pragma unroll
            for (int mt = 0; mt < 2; ++mt) {
                acc[mt][nt] = __builtin_amdgcn_mfma_f32_16x16x32_bf16(
                    ah[mt], bh, acc[mt][nt], 0, 0, 0);
                acc[mt][nt] = __builtin_amdgcn_mfma_f32_16x16x32_bf16(
                    ah[mt], bl, acc[mt][nt], 0, 0, 0);
                acc[mt][nt] = __builtin_amdgcn_mfma_f32_16x16x32_bf16(
                    al[mt], bh, acc[mt][nt], 0, 0, 0);
            }
        }
    };

    // ---- prologue: stage windows 0,1; then w(0) (stage older than w!) ----
    stage(0, 0);
    stage(1, 1);
    __builtin_amdgcn_sched_barrier(0);   // pin: w loads must issue after stages
    loadw(0, wrA);

    int b = 0;                            // buffer index of current window
#pragma unroll 1
    for (int win = 0; win < NWIN; win += 2) {
        // ---- even body: compute win from buf b with wrA ----
        // vmcnt(12) = keep {stage(win+1):4, w(win):8} in flight; everything
        // older (incl. stage(win)) is forced retired before the ds_reads.
        asm volatile("s_waitcnt vmcnt(12)" ::: "memory");
        __builtin_amdgcn_sched_barrier(0);
        {
            int b2 = b + 2; if (b2 >= 3) b2 -= 3;
            if (win + 2 < NWIN) stage(win + 2, b2);
            __builtin_amdgcn_sched_barrier(0);
            if (win + 1 < NWIN) loadw(win + 1, wrB);
            compute(b, wrA);
        }
        // ---- odd body: compute win+1 from buf (b+1)%3 with wrB ----
        asm volatile("s_waitcnt vmcnt(12)" ::: "memory");
        __builtin_amdgcn_sched_barrier(0);
        {
            int b1 = b + 1; if (b1 >= 3) b1 -= 3;
            if (win + 3 < NWIN) stage(win + 3, b);   // (win+3)%3 == b
            __builtin_amdgcn_sched_barrier(0);
            if (win + 2 < NWIN) loadw(win + 2, wrA);
            compute(b1, wrB);
        }
        b = (b + 2 >= 3) ? b - 1 : b + 2;            // b = (b+2)%3
    }

    // ---- cross-wave k-merge via LDS (staging region reused) ----
    __syncthreads();                    // all staging reads done before reuse
    f32x4* mg = (f32x4*)smem;           // [8 acc][4 wave][64 lane]
#pragma unroll
    for (int mt = 0; mt < 2; ++mt)
#pragma unroll
        for (int nt = 0; nt < 4; ++nt)
            mg[(size_t)(mt * 4 + nt) * 256 + wk * 64 + lane] = acc[mt][nt];
    __syncthreads();

    if (wk >= 2) return;
    const int mt = wk;              // wave 0 -> m-tile 0, wave 1 -> m-tile 1

    f32x4 a2[4];
#pragma unroll
    for (int nt = 0; nt < 4; ++nt) {
        f32x4 s = mg[(size_t)(mt * 4 + nt) * 256 + lane];
#pragma unroll
        for (int w = 1; w < 4; ++w)
            s += mg[(size_t)(mt * 4 + nt) * 256 + w * 64 + lane];
        a2[nt] = s;
    }

    float* logits   = out;
    float* idx_out  = out + (size_t)M * E;
    float* prob_out = idx_out + (size_t)M * 2;

    const int mrow = m0 + mt * 16 + quad * 4;
#pragma unroll
    for (int r = 0; r < 4; ++r) {
#pragma unroll
        for (int nt = 0; nt < 4; ++nt)
            logits[(size_t)(mrow + r) * E + nt * 16 + col] = a2[nt][r];

        // per-lane top-2 over its 4 experts (ascending index)
        float v1 = a2[0][r], v2 = -INFINITY;
        int   i1 = col,      i2 = 0x7fffffff;
#pragma unroll
        for (int nt = 1; nt < 4; ++nt) {
            const float v = a2[nt][r];
            const int   e = nt * 16 + col;
            if (v > v1)      { v2 = v1; i2 = i1; v1 = v; i1 = e; }
            else if (v > v2) { v2 = v;  i2 = e; }
        }
        // butterfly merge across the 16-lane row group
#pragma unroll
        for (int mask = 1; mask < 16; mask <<= 1) {
            const float ov1 = __shfl_xor(v1, mask);
            const float ov2 = __shfl_xor(v2, mask);
            const int   oi1 = __shfl_xor(i1, mask);
            const int   oi2 = __shfl_xor(i2, mask);
            const bool afirst = (v1 > ov1) || (v1 == ov1 && i1 < oi1);
            float nv1, nv2; int ni1, ni2;
            if (afirst) {
                nv1 = v1; ni1 = i1;
                const bool s = (v2 > ov1) || (v2 == ov1 && i2 < oi1);
                nv2 = s ? v2 : ov1; ni2 = s ? i2 : oi1;
            } else {
                nv1 = ov1; ni1 = oi1;
                const bool s = (ov2 > v1) || (ov2 == v1 && oi2 < i1);
                nv2 = s ? ov2 : v1; ni2 = s ? oi2 : i1;
            }
            v1 = nv1; v2 = nv2; i1 = ni1; i2 = ni2;
        }
        if (col == 0) {
            const int m = mrow + r;
            const float e2 = __expf(v2 - v1);   // <= 1
            const float d  = 1.0f + e2;
            *(float2*)(idx_out  + (size_t)m * 2) = make_float2((float)i1, (float)i2);
            *(float2*)(prob_out + (size_t)m * 2) = make_float2(1.0f / d, e2 / d);
        }
    }
}

extern "C" void kernel_launch(void* const* d_in, const int* in_sizes, int n_in,
                              void* d_out, int out_size, void* d_ws, size_t ws_size,
                              hipStream_t stream) {
    const float* x = (const float*)d_in[0];
    const float* w = (const float*)d_in[1];
    unsigned short* wh = (unsigned short*)d_ws;           // 512 KB
    unsigned short* wl = wh + (size_t)E * H;              // 512 KB
    const int M = in_sizes[0] / H;                        // 16384 rows

    hipLaunchKernelGGL(convert_w, dim3((E * H) / 1024), dim3(256), 0, stream,
                       w, wh, wl);
    hipLaunchKernelGGL(router_kernel, dim3(M / BMROWS), dim3(NT), 0, stream,
                       x, wh, wl, (float*)d_out, M);
}